// Round 1
// baseline (232.866 us; speedup 1.0000x reference)
//
#include <hip/hip_runtime.h>
#include <cstdint>
#include <cstddef>

// Problem constants: B=2, N=16384, K=32, F=64, E=16
#define LOGN 14
#define KNB 32

typedef __bf16 bf16x8 __attribute__((ext_vector_type(8)));
typedef float f32x4 __attribute__((ext_vector_type(4)));

__device__ __forceinline__ unsigned bf16rne(float f) {
  unsigned u = __builtin_bit_cast(unsigned, f);
  return (u + 0x7fffu + ((u >> 16) & 1u)) >> 16;
}

// wt[m][k] = w[l][m][n] / 32, k = l*16 + n  (bf16), 64x1024 = 128KB
__global__ void prep_wt(const float* __restrict__ w, unsigned short* __restrict__ wt) {
  int idx = blockIdx.x * 256 + threadIdx.x;   // 65536 total
  int m = idx >> 10;
  int k = idx & 1023;
  int l = k >> 4;
  int n = k & 15;
  float v = w[l * 1024 + m * 16 + n] * 0.03125f;
  wt[idx] = (unsigned short)bf16rne(v);
}

// One workgroup = 256 threads (4 waves) = 32 nodes.
// Phase A: wave w computes G (64l x 16n, fp32) for nodes w*8..w*8+7, stores bf16 to LDS.
//   LDS layout per node row (2048B = 128 x 16B chunks): logical chunk c = h*64 + l
//   (h = n-half), physically stored at c ^ (node&7) -> conflict-optimal b128 reads+writes.
// Phase B: wave w = m-tile w; C = 32 nodes x 16 m per wave; 32 K-steps of
//   mfma_f32_16x16x32_bf16, A from LDS, B from wt (global, L2-resident).
template <bool USE_WT>
__global__ __launch_bounds__(256, 2)
void mp_kernel(const float* __restrict__ nodes, const int* __restrict__ nlist,
               const float* __restrict__ edges, const unsigned short* __restrict__ wt,
               const float* __restrict__ w, float* __restrict__ out) {
  __shared__ uint4 g_lds[32 * 128];   // 64 KB
  const int tid = threadIdx.x;
  const int lane = tid & 63;
  const int wid = __builtin_amdgcn_readfirstlane(tid >> 6);
  const int wg0 = blockIdx.x << 5;    // first global node of this wg

  // ---------------- Phase A: G = sliced^T-outer-accumulate(edges) ----------------
  #pragma unroll 1
  for (int p = 0; p < 8; ++p) {
    const int nd = (wid << 3) + p;          // node in wg [0,32)
    const int g  = wg0 + nd;                // flat node id [0, 32768)
    const int b  = g >> LOGN;
    const float* __restrict__ nbase = nodes + ((size_t)b << 20);      // b*N*F
    const int* __restrict__ nl = nlist + ((size_t)g << 5);            // K ints
    const float4* __restrict__ ep4 = (const float4*)(edges + ((size_t)g << 9));

    float sv[KNB];
    #pragma unroll
    for (int j = 0; j < KNB; ++j) {
      const int ix = nl[j];                                  // wave-uniform -> s_load
      sv[j] = nbase[((size_t)(unsigned)ix << 6) + lane];     // coalesced 256B gather
    }

    float G[16];
    #pragma unroll
    for (int n = 0; n < 16; ++n) G[n] = 0.f;

    #pragma unroll
    for (int j = 0; j < KNB; ++j) {
      float e[16];
      *(float4*)&e[0]  = ep4[4 * j + 0];    // wave-uniform -> scalar loads
      *(float4*)&e[4]  = ep4[4 * j + 1];
      *(float4*)&e[8]  = ep4[4 * j + 2];
      *(float4*)&e[12] = ep4[4 * j + 3];
      const float s = sv[j];
      #pragma unroll
      for (int n = 0; n < 16; ++n) G[n] = fmaf(s, e[n], G[n]);
    }

    unsigned pk[8];
    #pragma unroll
    for (int h = 0; h < 8; ++h)
      pk[h] = bf16rne(G[2 * h]) | (bf16rne(G[2 * h + 1]) << 16);

    const int nxw = nd & 7;
    uint4* dst = g_lds + nd * 128;
    dst[lane ^ nxw]        = uint4{pk[0], pk[1], pk[2], pk[3]};   // h=0: n 0..7
    dst[64 + (lane ^ nxw)] = uint4{pk[4], pk[5], pk[6], pk[7]};   // h=1: n 8..15
  }

  __syncthreads();

  // ---------------- Phase B: out = G @ wt^T via MFMA ----------------
  const int col = lane & 15;            // A-row (node-in-tile) AND D-col (m) index
  const int q   = lane >> 4;
  const int mcol = (wid << 4) + col;    // m in [0,64)
  const int nx = col & 7;
  const int cbase = ((q & 1) << 6) + (q >> 1);   // logical chunk base: h*64 + l-offset
  const int row0 = col << 7;            // node col   (uint4 units, 128/row)
  const int row1 = (16 + col) << 7;     // node col+16

  f32x4 acc0 = {0.f, 0.f, 0.f, 0.f};
  f32x4 acc1 = {0.f, 0.f, 0.f, 0.f};

  if (USE_WT) {
    const unsigned short* bp = wt + ((size_t)mcol << 10) + (q << 3);
    #pragma unroll 4
    for (int s = 0; s < 32; ++s) {
      const int coff = (cbase + (s << 1)) ^ nx;
      bf16x8 a0 = __builtin_bit_cast(bf16x8, g_lds[row0 + coff]);
      bf16x8 a1 = __builtin_bit_cast(bf16x8, g_lds[row1 + coff]);
      bf16x8 bb = *(const bf16x8*)(bp + (s << 5));
      acc0 = __builtin_amdgcn_mfma_f32_16x16x32_bf16(a0, bb, acc0, 0, 0, 0);
      acc1 = __builtin_amdgcn_mfma_f32_16x16x32_bf16(a1, bb, acc1, 0, 0, 0);
    }
  } else {
    #pragma unroll 2
    for (int s = 0; s < 32; ++s) {
      const int coff = (cbase + (s << 1)) ^ nx;
      bf16x8 a0 = __builtin_bit_cast(bf16x8, g_lds[row0 + coff]);
      bf16x8 a1 = __builtin_bit_cast(bf16x8, g_lds[row1 + coff]);
      const int l = (s << 1) + (q >> 1);
      const float* wp = w + l * 1024 + mcol * 16 + ((q & 1) << 3);
      bf16x8 bb;
      #pragma unroll
      for (int jj = 0; jj < 8; ++jj) bb[jj] = (__bf16)(wp[jj] * 0.03125f);
      acc0 = __builtin_amdgcn_mfma_f32_16x16x32_bf16(a0, bb, acc0, 0, 0, 0);
      acc1 = __builtin_amdgcn_mfma_f32_16x16x32_bf16(a1, bb, acc1, 0, 0, 0);
    }
  }

  // D layout: col = lane&15 (m), row = q*4 + r (node-in-tile)
  #pragma unroll
  for (int r = 0; r < 4; ++r) {
    out[((size_t)(wg0 + (q << 2) + r) << 6) + mcol]      = acc0[r];
    out[((size_t)(wg0 + 16 + (q << 2) + r) << 6) + mcol] = acc1[r];
  }
}

extern "C" void kernel_launch(void* const* d_in, const int* in_sizes, int n_in,
                              void* d_out, int out_size, void* d_ws, size_t ws_size,
                              hipStream_t stream) {
  const float* nodes = (const float*)d_in[0];
  const int*   nlist = (const int*)d_in[1];
  const float* edges = (const float*)d_in[2];
  const float* w     = (const float*)d_in[3];
  float* out = (float*)d_out;

  if (ws_size >= 131072) {
    unsigned short* wt = (unsigned short*)d_ws;
    prep_wt<<<256, 256, 0, stream>>>(w, wt);
    mp_kernel<true><<<1024, 256, 0, stream>>>(nodes, nlist, edges, wt, w, out);
  } else {
    mp_kernel<false><<<1024, 256, 0, stream>>>(nodes, nlist, edges, nullptr, w, out);
  }
}